// Round 6
// baseline (5785.336 us; speedup 1.0000x reference)
//
#include <hip/hip_runtime.h>

typedef float v2f __attribute__((ext_vector_type(2)));
typedef float v4f __attribute__((ext_vector_type(4)));

#define D_IN 14
#define HID  32

#define LOG2E      1.4426950408889634f
#define TWO_LOG2E  2.8853900817779268f

#define NSCAN 4
#define NSPIN 48   // spinner blocks to hold the DVFS state up

__device__ __forceinline__ float rcpf(float x) { return __builtin_amdgcn_rcpf(x); }

#if __has_builtin(__builtin_amdgcn_exp2f)
__device__ __forceinline__ float exp2ff(float x) { return __builtin_amdgcn_exp2f(x); }
#else
__device__ __forceinline__ float exp2ff(float x) { return exp2f(x); }
#endif

// Exchange with lane^32 partner via v_permlane32_swap_b32 (proven r3/r5).
__device__ __forceinline__ float xchg32(float x) {
    float a = x, b;
    asm("v_mov_b32 %0, %1" : "=&v"(b) : "v"(x));
    asm("v_permlane32_swap_b32 %0, %1" : "+v"(a), "+v"(b));
    return (a + b) - x;
}

// Blocks 0..3: LSTM scan (wave 0 only), math bit-identical to round 5.
// Blocks 4..51: FMA spinners that keep the GPU busy until scan completes,
// to hold the clock governor at a high DPM state. They write nothing.
__global__ __launch_bounds__(256, 1)
void lstm_scan_boost(const float* __restrict__ x,
                     const float* __restrict__ W_ih,
                     const float* __restrict__ W_hh,
                     const float* __restrict__ b_ih,
                     const float* __restrict__ b_hh,
                     const float* __restrict__ Wt,  const float* __restrict__ bt,
                     const float* __restrict__ Wf1, const float* __restrict__ bf1,
                     const float* __restrict__ Wf2, const float* __restrict__ bf2,
                     float* __restrict__ hws,        // [128] final h
                     unsigned* __restrict__ flag,    // [0]=arrivals, [1]=done
                     float* __restrict__ out,
                     int T)
{
    __shared__ __align__(16) float hbuf[HID];
    __shared__ __align__(16) float dump[HID];

    const int blk = blockIdx.x;

    if (blk >= NSCAN) {
        // ---- spinner: real VALU work + low-rate device-scope poll ----
        unsigned* done = flag + 1;
        float a0 = 1.0f + (float)threadIdx.x;
        float a1 = 2.0f + (float)blk;
        for (;;) {
            #pragma unroll
            for (int k = 0; k < 128; ++k) {
                a0 = __builtin_fmaf(a0, 1.0000001f, 1.0e-7f);
                a1 = __builtin_fmaf(a1, 0.9999999f, 1.0e-7f);
            }
            asm volatile("" :: "v"(a0), "v"(a1));   // keep live
            if (__hip_atomic_load(done, __ATOMIC_ACQUIRE,
                                  __HIP_MEMORY_SCOPE_AGENT) != 0u) break;
        }
        return;
    }

    if (threadIdx.x >= 64) return;   // scan blocks: wave 0 only

    const int m    = blk;
    const int lane = threadIdx.x;
    const int hi   = lane >> 5;
    const int j    = lane & 31;
    const int rA   = lane;
    const int rB   = lane + 64;

    const float sA = -LOG2E;
    const float sB = hi ? -LOG2E : TWO_LOG2E;

    // ---- persistent prescaled weights in VGPRs ----
    v2f wah[16], wbh[16];
    {
        const v2f* pA = (const v2f*)(W_hh + (size_t)(m * 128 + rA) * HID);
        const v2f* pB = (const v2f*)(W_hh + (size_t)(m * 128 + rB) * HID);
        #pragma unroll
        for (int q = 0; q < 16; ++q) {
            v2f a = pA[q], b = pB[q];
            a.x *= sA; a.y *= sA; b.x *= sB; b.y *= sB;
            wah[q] = a; wbh[q] = b;
        }
    }
    v2f wax[7], wbx[7];
    {
        const v2f* pA = (const v2f*)(W_ih + (size_t)(m * 128 + rA) * D_IN);
        const v2f* pB = (const v2f*)(W_ih + (size_t)(m * 128 + rB) * D_IN);
        #pragma unroll
        for (int q = 0; q < 7; ++q) {
            v2f a = pA[q], b = pB[q];
            a.x *= sA; a.y *= sA; b.x *= sB; b.y *= sB;
            wax[q] = a; wbx[q] = b;
        }
    }
    const float bA = (b_ih[m * 128 + rA] + b_hh[m * 128 + rA]) * sA;
    const float bB = (b_ih[m * 128 + rB] + b_hh[m * 128 + rB]) * sB;

    const v2f* xs = (const v2f*)(x + (size_t)m * T * D_IN);
    v2f xb0[7], xb1[7];
    #pragma unroll
    for (int q = 0; q < 7; ++q) { xb0[q] = xs[q]; xb1[q] = xs[7 + q]; }

    float* hdst = hi ? &hbuf[j] : &dump[j];

    if (lane < 32) hbuf[lane] = 0.0f;
    float c = 0.0f;
    float vh = 0.0f;
    asm volatile("" ::: "memory");

#define STEP(t, xb)                                                            \
    {                                                                          \
        v2f av = {bA, 0.0f}, bv = {bB, 0.0f};                                  \
        _Pragma("unroll")                                                      \
        for (int q = 0; q < 7; ++q) {                                          \
            av = __builtin_elementwise_fma(wax[q], xb[q], av);                 \
            bv = __builtin_elementwise_fma(wbx[q], xb[q], bv);                 \
        }                                                                      \
        {                                                                      \
            int tn = (t) + 2; tn = (tn < T) ? tn : (T - 1);                    \
            const v2f* p = xs + (size_t)tn * 7;                                \
            _Pragma("unroll")                                                  \
            for (int q = 0; q < 7; ++q) xb[q] = p[q];                          \
        }                                                                      \
        v2f hv[16];                                                            \
        {                                                                      \
            const v4f* hp = (const v4f*)hbuf;                                  \
            _Pragma("unroll")                                                  \
            for (int q = 0; q < 8; ++q) {                                      \
                v4f t4 = hp[q];                                                \
                v2f hlo = {t4.x, t4.y};                                        \
                v2f hhi = {t4.z, t4.w};                                        \
                hv[2 * q]     = hlo;                                           \
                hv[2 * q + 1] = hhi;                                           \
            }                                                                  \
        }                                                                      \
        v2f a0 = av, a1 = {0.0f, 0.0f}, a2 = {0.0f, 0.0f}, a3 = {0.0f, 0.0f}; \
        v2f b0 = bv, b1 = {0.0f, 0.0f}, b2 = {0.0f, 0.0f}, b3 = {0.0f, 0.0f}; \
        _Pragma("unroll")                                                      \
        for (int q = 0; q < 16; q += 4) {                                      \
            a0 = __builtin_elementwise_fma(wah[q],     hv[q],     a0);         \
            a1 = __builtin_elementwise_fma(wah[q + 1], hv[q + 1], a1);         \
            a2 = __builtin_elementwise_fma(wah[q + 2], hv[q + 2], a2);         \
            a3 = __builtin_elementwise_fma(wah[q + 3], hv[q + 3], a3);         \
            b0 = __builtin_elementwise_fma(wbh[q],     hv[q],     b0);         \
            b1 = __builtin_elementwise_fma(wbh[q + 1], hv[q + 1], b1);         \
            b2 = __builtin_elementwise_fma(wbh[q + 2], hv[q + 2], b2);         \
            b3 = __builtin_elementwise_fma(wbh[q + 3], hv[q + 3], b3);         \
        }                                                                      \
        v2f as_ = (a0 + a1) + (a2 + a3);                                       \
        v2f bs_ = (b0 + b1) + (b2 + b3);                                       \
        float accA = as_.x + as_.y;                                            \
        float accB = bs_.x + bs_.y;                                            \
        float actA = rcpf(1.0f + exp2ff(accA));                                \
        float rBv  = rcpf(1.0f + exp2ff(accB));                                \
        float actB = hi ? rBv : __builtin_fmaf(-2.0f, rBv, 1.0f);              \
        float x0   = hi ? actA : actA * actB;                                  \
        float y0   = xchg32(x0);                                               \
        float sf   = hi ? actA : y0;                                           \
        float u    = hi ? y0   : x0;                                           \
        c = __builtin_fmaf(sf, c, u);                                          \
        float r2 = rcpf(1.0f + exp2ff(c * TWO_LOG2E));                         \
        float tc = __builtin_fmaf(-2.0f, r2, 1.0f);                            \
        vh = actB * tc;                                                        \
        *hdst = vh;                                                            \
        asm volatile("" ::: "memory");                                         \
    }

    for (int t = 0; t < T; t += 2) {
        STEP(t, xb0)
        STEP(t + 1, xb1)
    }
#undef STEP

    if (hi) hws[m * 32 + j] = vh;
    __threadfence();                      // device-scope release

    if (lane == 0) {
        unsigned old = atomicAdd(flag, 1u);
        if (old == (unsigned)(NSCAN - 1)) {   // last scan block: heads + done
            __threadfence();                  // acquire
            float s0 = bt[0];
            #pragma unroll
            for (int k = 0; k < 128; ++k) s0 += hws[k] * Wt[k];
            out[0] = s0;
            float s1 = bf1[0];
            #pragma unroll
            for (int k = 0; k < 32; ++k) s1 += hws[32 + k] * Wf1[k];
            out[1] = s1;
            float s2 = bf2[0];
            #pragma unroll
            for (int k = 0; k < 32; ++k) s2 += hws[64 + k] * Wf2[k];
            out[2] = s2;
            float s3 = bf2[0];
            #pragma unroll
            for (int k = 0; k < 32; ++k) s3 += hws[96 + k] * Wf2[k];
            out[3] = s3;
            __threadfence();
            __hip_atomic_store(flag + 1, 1u, __ATOMIC_RELEASE,
                               __HIP_MEMORY_SCOPE_AGENT);
        }
    }
}

extern "C" void kernel_launch(void* const* d_in, const int* in_sizes, int n_in,
                              void* d_out, int out_size, void* d_ws, size_t ws_size,
                              hipStream_t stream) {
    const float* x    = (const float*)d_in[0];
    const float* W_ih = (const float*)d_in[1];
    const float* W_hh = (const float*)d_in[2];
    const float* b_ih = (const float*)d_in[3];
    const float* b_hh = (const float*)d_in[4];
    const float* Wt   = (const float*)d_in[5];
    const float* bt   = (const float*)d_in[6];
    const float* Wf1  = (const float*)d_in[7];
    const float* bf1  = (const float*)d_in[8];
    const float* Wf2  = (const float*)d_in[9];
    const float* bf2  = (const float*)d_in[10];

    const int T = in_sizes[0] / (4 * D_IN);   // 16384

    unsigned* flag = (unsigned*)d_ws;                 // [0]=arrivals, [1]=done
    float*    hws  = (float*)((char*)d_ws + 256);     // 128 floats

    hipMemsetAsync(d_ws, 0, 256, stream);             // zero flags each call

    lstm_scan_boost<<<NSCAN + NSPIN, 256, 0, stream>>>(
        x, W_ih, W_hh, b_ih, b_hh,
        Wt, bt, Wf1, bf1, Wf2, bf2,
        hws, flag, (float*)d_out, T);
}

// Round 7
// 4550.504 us; speedup vs baseline: 1.2714x; 1.2714x over previous
//
#include <hip/hip_runtime.h>

typedef float v2f __attribute__((ext_vector_type(2)));

#define D_IN 14
#define HID  32

#define LOG2E      1.4426950408889634f
#define TWO_LOG2E  2.8853900817779268f

__device__ __forceinline__ float rcpf(float x) { return __builtin_amdgcn_rcpf(x); }

#if __has_builtin(__builtin_amdgcn_exp2f)
__device__ __forceinline__ float exp2ff(float x) { return __builtin_amdgcn_exp2f(x); }
#else
__device__ __forceinline__ float exp2ff(float x) { return exp2f(x); }
#endif

// DPP lane permute (within 16-lane row). All controls used are involutions,
// so semantics are direction-unambiguous:
//   0xB1 quad_perm[1,0,3,2]  -> lane ^ 1
//   0x4E quad_perm[2,3,0,1]  -> lane ^ 2
//   0x141 row_half_mirror    -> lane ^ 7
//   0x128 row_ror:8          -> lane ^ 8   (+8 == -8 mod 16)
template<int CTRL>
__device__ __forceinline__ float dppf(float x) {
    return __int_as_float(__builtin_amdgcn_mov_dpp(
        __float_as_int(x), CTRL, 0xf, 0xf, true));
}

// Direction-proof exchange with lane^32 partner (proven r3/r5: absmax 0.0).
__device__ __forceinline__ float xchg32(float x) {
    float a = x, b;
    asm("v_mov_b32 %0, %1" : "=&v"(b) : "v"(x));
    asm("v_permlane32_swap_b32 %0, %1" : "+v"(a), "+v"(b));
    return (a + b) - x;
}
// Same pattern for lane^16 (v_permlane16_swap_b32, gfx950). With a=b=x the
// pair {a,b} holds the two row-broadcast copies in either order, so
// (a+b)-x == partner's value under either direction convention.
__device__ __forceinline__ float xchg16(float x) {
    float a = x, b;
    asm("v_mov_b32 %0, %1" : "=&v"(b) : "v"(x));
    asm("v_permlane16_swap_b32 %0, %1" : "+v"(a), "+v"(b));
    return (a + b) - x;
}

// One LSTM per block (blockIdx.x = m), one wave of 64 lanes, private CU.
// Lane l: own gate rows rA=l (i|f), rB=l+64 (g|o); hi=l>>5; j=l&31.
// No LDS in the loop: h is held per-lane (every lane has true h[j]); the
// matvec gathers each lane's OWN 16-K-block via 15 DPP movs (weights
// pre-permuted to the slot order), computes 4 partial K=16 dots (own 2 rows
// + lane^16 partner's 2 rows), and completes K=32 with one permlane16_swap
// partial exchange.
__global__ __launch_bounds__(64, 1)
void lstm_scan_m(const float* __restrict__ x,
                 const float* __restrict__ W_ih,
                 const float* __restrict__ W_hh,
                 const float* __restrict__ b_ih,
                 const float* __restrict__ b_hh,
                 const float* __restrict__ Wt,  const float* __restrict__ bt,
                 const float* __restrict__ Wf1, const float* __restrict__ bf1,
                 const float* __restrict__ Wf2, const float* __restrict__ bf2,
                 float* __restrict__ hws,        // [128] final h
                 unsigned* __restrict__ flag,    // arrivals (zeroed per call)
                 float* __restrict__ out,
                 int T)
{
    const int m    = blockIdx.x;
    const int lane = threadIdx.x;      // 0..63
    const int hi   = lane >> 5;
    const int j    = lane & 31;
    const int rA   = lane;
    const int rB   = lane + 64;

    const float sA = -LOG2E;
    const float sB = hi ? -LOG2E : TWO_LOG2E;

    // slot s holds h[(j&16) | ((j&15) ^ mtab[s])] after the DPP gather
    const int mtab[16] = {0,1,2,3,7,6,5,4,8,9,10,11,15,14,13,12};
    const int j16 = j & 16, j15 = j & 15;
    int kk[16];
    #pragma unroll
    for (int s = 0; s < 16; ++s) kk[s] = j16 | (j15 ^ mtab[s]);

    // ---- pre-permuted, prescaled W_hh fragments (own + partner rows) ----
    const float* WOA = W_hh + (size_t)(m * 128 + rA) * HID;
    const float* WOB = W_hh + (size_t)(m * 128 + rB) * HID;
    const float* WPA = W_hh + (size_t)(m * 128 + (rA ^ 16)) * HID;
    const float* WPB = W_hh + (size_t)(m * 128 + (rB ^ 16)) * HID;
    v2f wOA[8], wOB[8], wPA[8], wPB[8];
    #pragma unroll
    for (int q = 0; q < 8; ++q) {
        wOA[q] = (v2f){WOA[kk[2*q]] * sA, WOA[kk[2*q+1]] * sA};
        wOB[q] = (v2f){WOB[kk[2*q]] * sB, WOB[kk[2*q+1]] * sB};
        wPA[q] = (v2f){WPA[kk[2*q]] * sA, WPA[kk[2*q+1]] * sA};
        wPB[q] = (v2f){WPB[kk[2*q]] * sB, WPB[kk[2*q+1]] * sB};
    }

    v2f wax[7], wbx[7];
    {
        const v2f* pA = (const v2f*)(W_ih + (size_t)(m * 128 + rA) * D_IN);
        const v2f* pB = (const v2f*)(W_ih + (size_t)(m * 128 + rB) * D_IN);
        #pragma unroll
        for (int q = 0; q < 7; ++q) {
            v2f a = pA[q], b = pB[q];
            a.x *= sA; a.y *= sA; b.x *= sB; b.y *= sB;
            wax[q] = a; wbx[q] = b;
        }
    }
    const float bA = (b_ih[m * 128 + rA] + b_hh[m * 128 + rA]) * sA;
    const float bB = (b_ih[m * 128 + rB] + b_hh[m * 128 + rB]) * sB;

    // x stream (wave-uniform address), ring-2 prefetch
    const v2f* xs = (const v2f*)(x + (size_t)m * T * D_IN);
    v2f xb0[7], xb1[7];
    #pragma unroll
    for (int q = 0; q < 7; ++q) { xb0[q] = xs[q]; xb1[q] = xs[7 + q]; }

    float c  = 0.0f;
    float vh = 0.0f;   // every lane: current h[j]

#define STEP(t, xb)                                                            \
    {                                                                          \
        /* registers-only gather of own 16-K-block (15 DPP movs) */            \
        float g0 = vh;                                                         \
        float g1 = dppf<0xB1>(g0);                                             \
        float g2 = dppf<0x4E>(g0), g3 = dppf<0x4E>(g1);                        \
        float g4 = dppf<0x141>(g0), g5 = dppf<0x141>(g1);                      \
        float g6 = dppf<0x141>(g2), g7 = dppf<0x141>(g3);                      \
        float g8 = dppf<0x128>(g0), g9 = dppf<0x128>(g1);                      \
        float gA = dppf<0x128>(g2), gB = dppf<0x128>(g3);                      \
        float gC = dppf<0x128>(g4), gD = dppf<0x128>(g5);                      \
        float gE = dppf<0x128>(g6), gF = dppf<0x128>(g7);                      \
        v2f hv[8];                                                             \
        hv[0] = (v2f){g0, g1}; hv[1] = (v2f){g2, g3};                          \
        hv[2] = (v2f){g4, g5}; hv[3] = (v2f){g6, g7};                          \
        hv[4] = (v2f){g8, g9}; hv[5] = (v2f){gA, gB};                          \
        hv[6] = (v2f){gC, gD}; hv[7] = (v2f){gE, gF};                          \
        /* x-part (off-chain, fills gather latency) */                         \
        v2f av = {bA, 0.0f}, bv = {bB, 0.0f};                                  \
        _Pragma("unroll")                                                      \
        for (int q = 0; q < 7; ++q) {                                          \
            av = __builtin_elementwise_fma(wax[q], xb[q], av);                 \
            bv = __builtin_elementwise_fma(wbx[q], xb[q], bv);                 \
        }                                                                      \
        {                                                                      \
            int tn = (t) + 2; tn = (tn < T) ? tn : (T - 1);                    \
            const v2f* p = xs + (size_t)tn * 7;                                \
            _Pragma("unroll")                                                  \
            for (int q = 0; q < 7; ++q) xb[q] = p[q];                          \
        }                                                                      \
        /* 4 partial dots (K=16): own rows + partner(lane^16) rows */          \
        v2f oa0 = av, oa1 = {0.0f, 0.0f}, ob0 = bv, ob1 = {0.0f, 0.0f};        \
        v2f pa0 = {0.0f, 0.0f}, pa1 = {0.0f, 0.0f};                            \
        v2f pb0 = {0.0f, 0.0f}, pb1 = {0.0f, 0.0f};                            \
        _Pragma("unroll")                                                      \
        for (int q = 0; q < 8; q += 2) {                                       \
            oa0 = __builtin_elementwise_fma(wOA[q],     hv[q],     oa0);       \
            oa1 = __builtin_elementwise_fma(wOA[q + 1], hv[q + 1], oa1);       \
            ob0 = __builtin_elementwise_fma(wOB[q],     hv[q],     ob0);       \
            ob1 = __builtin_elementwise_fma(wOB[q + 1], hv[q + 1], ob1);       \
            pa0 = __builtin_elementwise_fma(wPA[q],     hv[q],     pa0);       \
            pa1 = __builtin_elementwise_fma(wPA[q + 1], hv[q + 1], pa1);       \
            pb0 = __builtin_elementwise_fma(wPB[q],     hv[q],     pb0);       \
            pb1 = __builtin_elementwise_fma(wPB[q + 1], hv[q + 1], pb1);       \
        }                                                                      \
        v2f oas = oa0 + oa1, obs = ob0 + ob1;                                  \
        v2f pas = pa0 + pa1, pbs = pb0 + pb1;                                  \
        float qa = pas.x + pas.y, qb = pbs.x + pbs.y;                          \
        float ra = xchg16(qa), rb = xchg16(qb);   /* complete K=32 */          \
        float accA = (oas.x + oas.y) + ra;                                     \
        float accB = (obs.x + obs.y) + rb;                                     \
        /* activations on prescaled accs */                                    \
        float actA = rcpf(1.0f + exp2ff(accA));           /* sig(i)|sig(f) */  \
        float rBv  = rcpf(1.0f + exp2ff(accB));                                \
        float actB = hi ? rBv : __builtin_fmaf(-2.0f, rBv, 1.0f);              \
        float x0   = hi ? actA : actA * actB;             /* sig(f) | u */     \
        float y0   = xchg32(x0);                          /* u | sig(f) */     \
        float y1   = xchg32(actB);                        /* so to lo lanes */ \
        float sf   = hi ? actA : y0;                                           \
        float u    = hi ? y0   : x0;                                           \
        c = __builtin_fmaf(sf, c, u);                                          \
        float so = hi ? actB : y1;                                             \
        float r2 = rcpf(1.0f + exp2ff(c * TWO_LOG2E));                         \
        float tc = __builtin_fmaf(-2.0f, r2, 1.0f);                            \
        vh = so * tc;                       /* every lane: true h[j] */        \
    }

    for (int t = 0; t < T; t += 2) {
        STEP(t, xb0)
        STEP(t + 1, xb1)
    }
#undef STEP

    // publish final h (hi lanes' copy is canonical)
    if (hi) hws[m * 32 + j] = vh;
    __threadfence();                      // device-scope release

    if (lane == 0) {
        unsigned old = atomicAdd(flag, 1u);
        if (old == 3u) {                  // last block computes all heads
            __threadfence();              // acquire
            float s0 = bt[0];
            #pragma unroll
            for (int k = 0; k < 128; ++k) s0 += hws[k] * Wt[k];
            out[0] = s0;
            float s1 = bf1[0];
            #pragma unroll
            for (int k = 0; k < 32; ++k) s1 += hws[32 + k] * Wf1[k];
            out[1] = s1;
            float s2 = bf2[0];
            #pragma unroll
            for (int k = 0; k < 32; ++k) s2 += hws[64 + k] * Wf2[k];
            out[2] = s2;
            float s3 = bf2[0];
            #pragma unroll
            for (int k = 0; k < 32; ++k) s3 += hws[96 + k] * Wf2[k];
            out[3] = s3;
        }
    }
}

extern "C" void kernel_launch(void* const* d_in, const int* in_sizes, int n_in,
                              void* d_out, int out_size, void* d_ws, size_t ws_size,
                              hipStream_t stream) {
    const float* x    = (const float*)d_in[0];
    const float* W_ih = (const float*)d_in[1];
    const float* W_hh = (const float*)d_in[2];
    const float* b_ih = (const float*)d_in[3];
    const float* b_hh = (const float*)d_in[4];
    const float* Wt   = (const float*)d_in[5];
    const float* bt   = (const float*)d_in[6];
    const float* Wf1  = (const float*)d_in[7];
    const float* bf1  = (const float*)d_in[8];
    const float* Wf2  = (const float*)d_in[9];
    const float* bf2  = (const float*)d_in[10];

    const int T = in_sizes[0] / (4 * D_IN);   // 16384

    unsigned* flag = (unsigned*)d_ws;                 // 4 B counter
    float*    hws  = (float*)((char*)d_ws + 256);     // 128 floats

    hipMemsetAsync(d_ws, 0, 256, stream);             // zero flag each call

    lstm_scan_m<<<4, 64, 0, stream>>>(x, W_ih, W_hh, b_ih, b_hh,
                                      Wt, bt, Wf1, bf1, Wf2, bf2,
                                      hws, flag, (float*)d_out, T);
}

// Round 9
// 4523.692 us; speedup vs baseline: 1.2789x; 1.0059x over previous
//
#include <hip/hip_runtime.h>

typedef float v2f __attribute__((ext_vector_type(2)));

#define D_IN 14
#define HID  32

#define LOG2E      1.4426950408889634f
#define TWO_LOG2E  2.8853900817779268f

__device__ __forceinline__ float rcpf(float x) { return __builtin_amdgcn_rcpf(x); }

#if __has_builtin(__builtin_amdgcn_exp2f)
__device__ __forceinline__ float exp2ff(float x) { return __builtin_amdgcn_exp2f(x); }
#else
__device__ __forceinline__ float exp2ff(float x) { return exp2f(x); }
#endif

// DPP lane permute within a 16-lane row. 0x121..0x12F = row_ror:1..15.
// Each rotation is an INDEPENDENT depth-1 op sourced from the same register,
// so the h-gather has cross-lane dependency depth 1 (vs depth-4 XOR tree).
template<int CTRL>
__device__ __forceinline__ float dppf(float x) {
    return __int_as_float(__builtin_amdgcn_mov_dpp(
        __float_as_int(x), CTRL, 0xf, 0xf, true));
}

// Direction-proof exchanges (proven r3/r5/r7: absmax 0.0).
__device__ __forceinline__ float xchg32(float x) {
    float a = x, b;
    asm("v_mov_b32 %0, %1" : "=&v"(b) : "v"(x));
    asm("v_permlane32_swap_b32 %0, %1" : "+v"(a), "+v"(b));
    return (a + b) - x;
}
__device__ __forceinline__ float xchg16(float x) {
    float a = x, b;
    asm("v_mov_b32 %0, %1" : "=&v"(b) : "v"(x));
    asm("v_permlane16_swap_b32 %0, %1" : "+v"(a), "+v"(b));
    return (a + b) - x;
}

// One LSTM per block (blockIdx.x = m), one wave of 64 lanes, private CU.
// Lane l: own gate rows rA=l (i|f), rB=l+64 (g|o); hi=l>>5; j=l&31.
// h held per-lane (every lane has true h[j]). Gather of the lane's 16-K
// block = 15 independent row_ror DPPs (depth 1). Weights pre-permuted to
// the rotation order, direction resolved by a runtime probe. 4 partial
// K=16 dots (own 2 rows + lane^16 partner's 2 rows), completed to K=32
// with one permlane16_swap partial exchange. No LDS in the loop.
__global__ __launch_bounds__(64, 1)
void lstm_scan_m(const float* __restrict__ x,
                 const float* __restrict__ W_ih,
                 const float* __restrict__ W_hh,
                 const float* __restrict__ b_ih,
                 const float* __restrict__ b_hh,
                 const float* __restrict__ Wt,  const float* __restrict__ bt,
                 const float* __restrict__ Wf1, const float* __restrict__ bf1,
                 const float* __restrict__ Wf2, const float* __restrict__ bf2,
                 float* __restrict__ hws,        // [128] final h
                 unsigned* __restrict__ flag,    // arrivals (zeroed per call)
                 float* __restrict__ out,
                 int T)
{
    const int m    = blockIdx.x;
    const int lane = threadIdx.x;      // 0..63
    const int hi   = lane >> 5;
    const int j    = lane & 31;
    const int rA   = lane;
    const int rB   = lane + 64;

    const float sA = -LOG2E;
    const float sB = hi ? -LOG2E : TWO_LOG2E;

    // Probe row_ror direction: slot s holds h[j16 | ((j15 + s*d0) & 15)]
    // where d0 = src-lane offset of row_ror:1 (1 or 15, either works mod 16).
    int d0;
    {
        int p = __builtin_amdgcn_mov_dpp(lane, 0x121, 0xf, 0xf, true);
        d0 = __builtin_amdgcn_readfirstlane(p);   // lane0's source lane: 1 or 15
    }
    const int j16 = j & 16, j15 = j & 15;
    int kk[16];
    #pragma unroll
    for (int s = 0; s < 16; ++s) kk[s] = j16 | ((j15 + s * d0) & 15);

    // ---- pre-permuted, prescaled W_hh fragments (own + partner rows) ----
    const float* WOA = W_hh + (size_t)(m * 128 + rA) * HID;
    const float* WOB = W_hh + (size_t)(m * 128 + rB) * HID;
    const float* WPA = W_hh + (size_t)(m * 128 + (rA ^ 16)) * HID;
    const float* WPB = W_hh + (size_t)(m * 128 + (rB ^ 16)) * HID;
    v2f wOA[8], wOB[8], wPA[8], wPB[8];
    #pragma unroll
    for (int q = 0; q < 8; ++q) {
        wOA[q] = (v2f){WOA[kk[2*q]] * sA, WOA[kk[2*q+1]] * sA};
        wOB[q] = (v2f){WOB[kk[2*q]] * sB, WOB[kk[2*q+1]] * sB};
        wPA[q] = (v2f){WPA[kk[2*q]] * sA, WPA[kk[2*q+1]] * sA};
        wPB[q] = (v2f){WPB[kk[2*q]] * sB, WPB[kk[2*q+1]] * sB};
    }

    v2f wax[7], wbx[7];
    {
        const v2f* pA = (const v2f*)(W_ih + (size_t)(m * 128 + rA) * D_IN);
        const v2f* pB = (const v2f*)(W_ih + (size_t)(m * 128 + rB) * D_IN);
        #pragma unroll
        for (int q = 0; q < 7; ++q) {
            v2f a = pA[q], b = pB[q];
            a.x *= sA; a.y *= sA; b.x *= sB; b.y *= sB;
            wax[q] = a; wbx[q] = b;
        }
    }
    const float bA = (b_ih[m * 128 + rA] + b_hh[m * 128 + rA]) * sA;
    const float bB = (b_ih[m * 128 + rB] + b_hh[m * 128 + rB]) * sB;

    // x stream (wave-uniform address), ring-2 prefetch
    const v2f* xs = (const v2f*)(x + (size_t)m * T * D_IN);
    v2f xb0[7], xb1[7];
    #pragma unroll
    for (int q = 0; q < 7; ++q) { xb0[q] = xs[q]; xb1[q] = xs[7 + q]; }

    float c  = 0.0f;
    float vh = 0.0f;   // every lane: current h[j]

#define STEP(t, xb)                                                            \
    {                                                                          \
        /* depth-1 gather: 15 independent row_ror DPPs of vh */                \
        float g1 = dppf<0x121>(vh), g2 = dppf<0x122>(vh);                      \
        float g3 = dppf<0x123>(vh), g4 = dppf<0x124>(vh);                      \
        float g5 = dppf<0x125>(vh), g6 = dppf<0x126>(vh);                      \
        float g7 = dppf<0x127>(vh), g8 = dppf<0x128>(vh);                      \
        float g9 = dppf<0x129>(vh), gA = dppf<0x12A>(vh);                      \
        float gB = dppf<0x12B>(vh), gC = dppf<0x12C>(vh);                      \
        float gD = dppf<0x12D>(vh), gE = dppf<0x12E>(vh);                      \
        float gF = dppf<0x12F>(vh);                                            \
        v2f hv[8];                                                             \
        hv[0] = (v2f){vh, g1}; hv[1] = (v2f){g2, g3};                          \
        hv[2] = (v2f){g4, g5}; hv[3] = (v2f){g6, g7};                          \
        hv[4] = (v2f){g8, g9}; hv[5] = (v2f){gA, gB};                          \
        hv[6] = (v2f){gC, gD}; hv[7] = (v2f){gE, gF};                          \
        /* x-part (off-chain, fills gather latency) */                         \
        v2f av = {bA, 0.0f}, bv = {bB, 0.0f};                                  \
        _Pragma("unroll")                                                      \
        for (int q = 0; q < 7; ++q) {                                          \
            av = __builtin_elementwise_fma(wax[q], xb[q], av);                 \
            bv = __builtin_elementwise_fma(wbx[q], xb[q], bv);                 \
        }                                                                      \
        {                                                                      \
            int tn = (t) + 2; tn = (tn < T) ? tn : (T - 1);                    \
            const v2f* p = xs + (size_t)tn * 7;                                \
            _Pragma("unroll")                                                  \
            for (int q = 0; q < 7; ++q) xb[q] = p[q];                          \
        }                                                                      \
        /* 4 partial dots (K=16): own rows + partner(lane^16) rows */          \
        v2f oa0 = av, oa1 = {0.0f, 0.0f}, ob0 = bv, ob1 = {0.0f, 0.0f};        \
        v2f pa0 = {0.0f, 0.0f}, pa1 = {0.0f, 0.0f};                            \
        v2f pb0 = {0.0f, 0.0f}, pb1 = {0.0f, 0.0f};                            \
        _Pragma("unroll")                                                      \
        for (int q = 0; q < 8; q += 2) {                                       \
            oa0 = __builtin_elementwise_fma(wOA[q],     hv[q],     oa0);       \
            oa1 = __builtin_elementwise_fma(wOA[q + 1], hv[q + 1], oa1);       \
            ob0 = __builtin_elementwise_fma(wOB[q],     hv[q],     ob0);       \
            ob1 = __builtin_elementwise_fma(wOB[q + 1], hv[q + 1], ob1);       \
            pa0 = __builtin_elementwise_fma(wPA[q],     hv[q],     pa0);       \
            pa1 = __builtin_elementwise_fma(wPA[q + 1], hv[q + 1], pa1);       \
            pb0 = __builtin_elementwise_fma(wPB[q],     hv[q],     pb0);       \
            pb1 = __builtin_elementwise_fma(wPB[q + 1], hv[q + 1], pb1);       \
        }                                                                      \
        v2f oas = oa0 + oa1, obs = ob0 + ob1;                                  \
        v2f pas = pa0 + pa1, pbs = pb0 + pb1;                                  \
        float qa = pas.x + pas.y, qb = pbs.x + pbs.y;                          \
        float ra = xchg16(qa), rb = xchg16(qb);   /* complete K=32 */          \
        float accA = (oas.x + oas.y) + ra;                                     \
        float accB = (obs.x + obs.y) + rb;                                     \
        /* activations on prescaled accs */                                    \
        float actA = rcpf(1.0f + exp2ff(accA));           /* sig(i)|sig(f) */  \
        float rBv  = rcpf(1.0f + exp2ff(accB));                                \
        float actB = hi ? rBv : __builtin_fmaf(-2.0f, rBv, 1.0f);              \
        float x0   = hi ? actA : actA * actB;             /* sig(f) | u */     \
        float y0   = xchg32(x0);                          /* u | sig(f) */     \
        float y1   = xchg32(actB);                        /* so to lo lanes */ \
        float sf   = hi ? actA : y0;                                           \
        float u    = hi ? y0   : x0;                                           \
        c = __builtin_fmaf(sf, c, u);                                          \
        float so = hi ? actB : y1;                                             \
        float r2 = rcpf(1.0f + exp2ff(c * TWO_LOG2E));                         \
        float tc = __builtin_fmaf(-2.0f, r2, 1.0f);                            \
        vh = so * tc;                       /* every lane: true h[j] */        \
    }

    for (int t = 0; t < T; t += 2) {
        STEP(t, xb0)
        STEP(t + 1, xb1)
    }
#undef STEP

    // publish final h (hi lanes' copy is canonical)
    if (hi) hws[m * 32 + j] = vh;
    __threadfence();                      // device-scope release

    if (lane == 0) {
        unsigned old = atomicAdd(flag, 1u);
        if (old == 3u) {                  // last block computes all heads
            __threadfence();              // acquire
            float s0 = bt[0];
            #pragma unroll
            for (int k = 0; k < 128; ++k) s0 += hws[k] * Wt[k];
            out[0] = s0;
            float s1 = bf1[0];
            #pragma unroll
            for (int k = 0; k < 32; ++k) s1 += hws[32 + k] * Wf1[k];
            out[1] = s1;
            float s2 = bf2[0];
            #pragma unroll
            for (int k = 0; k < 32; ++k) s2 += hws[64 + k] * Wf2[k];
            out[2] = s2;
            float s3 = bf2[0];
            #pragma unroll
            for (int k = 0; k < 32; ++k) s3 += hws[96 + k] * Wf2[k];
            out[3] = s3;
        }
    }
}

extern "C" void kernel_launch(void* const* d_in, const int* in_sizes, int n_in,
                              void* d_out, int out_size, void* d_ws, size_t ws_size,
                              hipStream_t stream) {
    const float* x    = (const float*)d_in[0];
    const float* W_ih = (const float*)d_in[1];
    const float* W_hh = (const float*)d_in[2];
    const float* b_ih = (const float*)d_in[3];
    const float* b_hh = (const float*)d_in[4];
    const float* Wt   = (const float*)d_in[5];
    const float* bt   = (const float*)d_in[6];
    const float* Wf1  = (const float*)d_in[7];
    const float* bf1  = (const float*)d_in[8];
    const float* Wf2  = (const float*)d_in[9];
    const float* bf2  = (const float*)d_in[10];

    const int T = in_sizes[0] / (4 * D_IN);   // 16384

    unsigned* flag = (unsigned*)d_ws;                 // 4 B counter
    float*    hws  = (float*)((char*)d_ws + 256);     // 128 floats

    hipMemsetAsync(d_ws, 0, 256, stream);             // zero flag each call

    lstm_scan_m<<<4, 64, 0, stream>>>(x, W_ih, W_hh, b_ih, b_hh,
                                      Wt, bt, Wf1, bf1, Wf2, bf2,
                                      hws, flag, (float*)d_out, T);
}

// Round 10
// 3671.698 us; speedup vs baseline: 1.5757x; 1.2320x over previous
//
#include <hip/hip_runtime.h>

typedef float v2f __attribute__((ext_vector_type(2)));
typedef float v4f __attribute__((ext_vector_type(4)));

#define D_IN 14
#define HID  32
#define XT   16   // timesteps per xproj block

#define LOG2E      1.4426950408889634f
#define TWO_LOG2E  2.8853900817779268f

__device__ __forceinline__ float rcpf(float x) { return __builtin_amdgcn_rcpf(x); }

#if __has_builtin(__builtin_amdgcn_exp2f)
__device__ __forceinline__ float exp2ff(float x) { return __builtin_amdgcn_exp2f(x); }
#else
__device__ __forceinline__ float exp2ff(float x) { return exp2f(x); }
#endif

// DPP row_ror:N (0x120+N): independent depth-1 rotations within 16-lane rows.
template<int CTRL>
__device__ __forceinline__ float dppf(float x) {
    return __int_as_float(__builtin_amdgcn_mov_dpp(
        __float_as_int(x), CTRL, 0xf, 0xf, true));
}

// Direction-proof exchanges (proven r3/r5/r7/r9: absmax 0.0).
__device__ __forceinline__ float xchg32(float x) {
    float a = x, b;
    asm("v_mov_b32 %0, %1" : "=&v"(b) : "v"(x));
    asm("v_permlane32_swap_b32 %0, %1" : "+v"(a), "+v"(b));
    return (a + b) - x;
}
__device__ __forceinline__ float xchg16(float x) {
    float a = x, b;
    asm("v_mov_b32 %0, %1" : "=&v"(b) : "v"(x));
    asm("v_permlane16_swap_b32 %0, %1" : "+v"(a), "+v"(b));
    return (a + b) - x;
}

// ---------------- phase 1: x projection (parallel, bit-exact) ----------
// Computes EXACTLY the v2f accumulator r9's in-loop x-part produced:
//   acc = {bias*sc, 0}; 7x acc = fma(w*sc, x2, acc)   (v2f lanes kept!)
// and stores the UNROUNDED pair. Layout: xp[t][m][lane 0..63][4] floats,
// where lane slot = {accA.x, accA.y, accB.x, accB.y} for rows (lane, lane+64).
__global__ __launch_bounds__(128)
void xproj_kernel(const float* __restrict__ x,
                  const float* __restrict__ W_ih,
                  const float* __restrict__ b_ih,
                  const float* __restrict__ b_hh,
                  float* __restrict__ xp,
                  int t0, int cT, int T)
{
    const int m = blockIdx.y;
    const int r = threadIdx.x;            // gate row 0..127
    const int tlo = blockIdx.x * XT;

    const float sc = (r < 64) ? -LOG2E : ((r < 96) ? TWO_LOG2E : -LOG2E);

    v2f w[7];
    const v2f* wp = (const v2f*)(W_ih + (size_t)(m * 128 + r) * D_IN);
    #pragma unroll
    for (int q = 0; q < 7; ++q) {
        v2f t = wp[q]; t.x *= sc; t.y *= sc; w[q] = t;
    }
    const float bs = (b_ih[m * 128 + r] + b_hh[m * 128 + r]) * sc;

    #pragma unroll
    for (int tt = 0; tt < XT; ++tt) {
        int t = tlo + tt;
        if (t >= cT) break;
        const v2f* xr = (const v2f*)(x + ((size_t)m * T + t0 + t) * D_IN);
        v2f acc = {bs, 0.0f};
        #pragma unroll
        for (int q = 0; q < 7; ++q) acc = __builtin_elementwise_fma(w[q], xr[q], acc);
        float* dst = xp + (((size_t)t * 4 + m) * 64 + (r & 63)) * 4 + (r >> 6) * 2;
        *(v2f*)dst = acc;   // unrounded v2f pair
    }
}

// ---------------- phase 2: sequential scan (4 blocks, 1 wave each) -------
// Math bit-identical to round 9 (passed, absmax 0.0): same DPP gather, same
// partner-row split, same exchanges and activations. Only change: the x-part
// v2f accumulators arrive preloaded from xp (one dwordx4 per lane per step,
// ring-8 prefetched). Persistent register demand ~130 (was ~150+ with W_ih).
__global__ __launch_bounds__(64, 1)
void lstm_scan_m(const float* __restrict__ xp,
                 const float* __restrict__ W_hh,
                 float* __restrict__ carry,   // [0..127] h, [128..255] c
                 int cT, int first)
{
    const int m    = blockIdx.x;
    const int lane = threadIdx.x;      // 0..63
    const int hi   = lane >> 5;
    const int j    = lane & 31;
    const int rA   = lane;
    const int rB   = lane + 64;

    const float sA = -LOG2E;
    const float sB = hi ? -LOG2E : TWO_LOG2E;

    // Probe row_ror direction (slot s holds h[j16 | ((j15 + s*d0)&15)]).
    int d0;
    {
        int p = __builtin_amdgcn_mov_dpp(lane, 0x121, 0xf, 0xf, true);
        d0 = __builtin_amdgcn_readfirstlane(p);
    }
    const int j16 = j & 16, j15 = j & 15;
    int kk[16];
    #pragma unroll
    for (int s = 0; s < 16; ++s) kk[s] = j16 | ((j15 + s * d0) & 15);

    // pre-permuted, prescaled W_hh fragments (own + partner rows)
    const float* WOA = W_hh + (size_t)(m * 128 + rA) * HID;
    const float* WOB = W_hh + (size_t)(m * 128 + rB) * HID;
    const float* WPA = W_hh + (size_t)(m * 128 + (rA ^ 16)) * HID;
    const float* WPB = W_hh + (size_t)(m * 128 + (rB ^ 16)) * HID;
    v2f wOA[8], wOB[8], wPA[8], wPB[8];
    #pragma unroll
    for (int q = 0; q < 8; ++q) {
        wOA[q] = (v2f){WOA[kk[2*q]] * sA, WOA[kk[2*q+1]] * sA};
        wOB[q] = (v2f){WOB[kk[2*q]] * sB, WOB[kk[2*q+1]] * sB};
        wPA[q] = (v2f){WPA[kk[2*q]] * sA, WPA[kk[2*q+1]] * sA};
        wPB[q] = (v2f){WPB[kk[2*q]] * sB, WPB[kk[2*q+1]] * sB};
    }

    // per-lane xp stream: v4f index (t*256 + m*64 + lane)
    const v4f* xpv = (const v4f*)xp + (size_t)m * 64 + lane;

    float c, vh;
    if (first) { c = 0.0f; vh = 0.0f; }
    else       { vh = carry[m * 32 + j]; c = carry[128 + m * 32 + j]; }

    // ring-8 prefetch (static slot names -> stays in registers)
    v4f s0, s1, s2, s3, s4, s5, s6, s7;
    {
        int e = cT - 1;
        s0 = xpv[(size_t)((0 < e) ? 0 : e) * 256];
        s1 = xpv[(size_t)((1 < e) ? 1 : e) * 256];
        s2 = xpv[(size_t)((2 < e) ? 2 : e) * 256];
        s3 = xpv[(size_t)((3 < e) ? 3 : e) * 256];
        s4 = xpv[(size_t)((4 < e) ? 4 : e) * 256];
        s5 = xpv[(size_t)((5 < e) ? 5 : e) * 256];
        s6 = xpv[(size_t)((6 < e) ? 6 : e) * 256];
        s7 = xpv[(size_t)((7 < e) ? 7 : e) * 256];
    }

#define STEP(t, X)                                                             \
    {                                                                          \
        /* depth-1 gather: 15 independent row_ror DPPs of vh */                \
        float g1 = dppf<0x121>(vh), g2 = dppf<0x122>(vh);                      \
        float g3 = dppf<0x123>(vh), g4 = dppf<0x124>(vh);                      \
        float g5 = dppf<0x125>(vh), g6 = dppf<0x126>(vh);                      \
        float g7 = dppf<0x127>(vh), g8 = dppf<0x128>(vh);                      \
        float g9 = dppf<0x129>(vh), gA = dppf<0x12A>(vh);                      \
        float gB = dppf<0x12B>(vh), gC = dppf<0x12C>(vh);                      \
        float gD = dppf<0x12D>(vh), gE = dppf<0x12E>(vh);                      \
        float gF = dppf<0x12F>(vh);                                            \
        v2f hv[8];                                                             \
        hv[0] = (v2f){vh, g1}; hv[1] = (v2f){g2, g3};                          \
        hv[2] = (v2f){g4, g5}; hv[3] = (v2f){g6, g7};                          \
        hv[4] = (v2f){g8, g9}; hv[5] = (v2f){gA, gB};                          \
        hv[6] = (v2f){gC, gD}; hv[7] = (v2f){gE, gF};                          \
        /* 4 partial dots (K=16), seeded by the PRELOADED x-accumulators */    \
        v2f oa0 = (v2f){X.x, X.y}, oa1 = {0.0f, 0.0f};                         \
        v2f ob0 = (v2f){X.z, X.w}, ob1 = {0.0f, 0.0f};                         \
        v2f pa0 = {0.0f, 0.0f}, pa1 = {0.0f, 0.0f};                            \
        v2f pb0 = {0.0f, 0.0f}, pb1 = {0.0f, 0.0f};                            \
        _Pragma("unroll")                                                      \
        for (int q = 0; q < 8; q += 2) {                                       \
            oa0 = __builtin_elementwise_fma(wOA[q],     hv[q],     oa0);       \
            oa1 = __builtin_elementwise_fma(wOA[q + 1], hv[q + 1], oa1);       \
            ob0 = __builtin_elementwise_fma(wOB[q],     hv[q],     ob0);       \
            ob1 = __builtin_elementwise_fma(wOB[q + 1], hv[q + 1], ob1);       \
            pa0 = __builtin_elementwise_fma(wPA[q],     hv[q],     pa0);       \
            pa1 = __builtin_elementwise_fma(wPA[q + 1], hv[q + 1], pa1);       \
            pb0 = __builtin_elementwise_fma(wPB[q],     hv[q],     pb0);       \
            pb1 = __builtin_elementwise_fma(wPB[q + 1], hv[q + 1], pb1);       \
        }                                                                      \
        /* prefetch xp for t+8 into the slot just consumed */                  \
        {                                                                      \
            int tn = (t) + 8; tn = (tn < cT) ? tn : (cT - 1);                  \
            X = xpv[(size_t)tn * 256];                                         \
        }                                                                      \
        v2f oas = oa0 + oa1, obs = ob0 + ob1;                                  \
        v2f pas = pa0 + pa1, pbs = pb0 + pb1;                                  \
        float qa = pas.x + pas.y, qb = pbs.x + pbs.y;                          \
        float ra = xchg16(qa), rb = xchg16(qb);   /* complete K=32 */          \
        float accA = (oas.x + oas.y) + ra;                                     \
        float accB = (obs.x + obs.y) + rb;                                     \
        float actA = rcpf(1.0f + exp2ff(accA));           /* sig(i)|sig(f) */  \
        float rBv  = rcpf(1.0f + exp2ff(accB));                                \
        float actB = hi ? rBv : __builtin_fmaf(-2.0f, rBv, 1.0f);              \
        float x0   = hi ? actA : actA * actB;             /* sig(f) | u */     \
        float y0   = xchg32(x0);                          /* u | sig(f) */     \
        float y1   = xchg32(actB);                        /* so -> lo lanes */ \
        float sf   = hi ? actA : y0;                                           \
        float u    = hi ? y0   : x0;                                           \
        c = __builtin_fmaf(sf, c, u);                                          \
        float so = hi ? actB : y1;                                             \
        float r2 = rcpf(1.0f + exp2ff(c * TWO_LOG2E));                         \
        float tc = __builtin_fmaf(-2.0f, r2, 1.0f);                            \
        vh = so * tc;                       /* every lane: true h[j] */        \
    }

    int t = 0;
    for (; t + 8 <= cT; t += 8) {
        STEP(t,     s0)
        STEP(t + 1, s1)
        STEP(t + 2, s2)
        STEP(t + 3, s3)
        STEP(t + 4, s4)
        STEP(t + 5, s5)
        STEP(t + 6, s6)
        STEP(t + 7, s7)
    }
    for (; t < cT; ++t) {   // defensive tail (cT kept a multiple of 8)
        v4f q4 = xpv[(size_t)t * 256];
        STEP(t, q4)
    }
#undef STEP

    // carry out h,c (hi lanes canonical; identical values in lo lanes)
    if (hi) {
        carry[m * 32 + j]       = vh;
        carry[128 + m * 32 + j] = c;
    }
}

// ---------------- phase 3: heads ----------------
__global__ __launch_bounds__(64)
void heads_kernel(const float* __restrict__ carry,
                  const float* __restrict__ Wt,  const float* __restrict__ bt,
                  const float* __restrict__ Wf1, const float* __restrict__ bf1,
                  const float* __restrict__ Wf2, const float* __restrict__ bf2,
                  float* __restrict__ out)
{
    const int tid = threadIdx.x;
    if (tid == 0) {
        float s = bt[0];
        #pragma unroll
        for (int k = 0; k < 128; ++k) s += carry[k] * Wt[k];
        out[0] = s;
    } else if (tid == 1) {
        float s = bf1[0];
        #pragma unroll
        for (int k = 0; k < 32; ++k) s += carry[32 + k] * Wf1[k];
        out[1] = s;
    } else if (tid == 2) {
        float s = bf2[0];
        #pragma unroll
        for (int k = 0; k < 32; ++k) s += carry[64 + k] * Wf2[k];
        out[2] = s;
    } else if (tid == 3) {
        float s = bf2[0];
        #pragma unroll
        for (int k = 0; k < 32; ++k) s += carry[96 + k] * Wf2[k];
        out[3] = s;
    }
}

extern "C" void kernel_launch(void* const* d_in, const int* in_sizes, int n_in,
                              void* d_out, int out_size, void* d_ws, size_t ws_size,
                              hipStream_t stream) {
    const float* x    = (const float*)d_in[0];
    const float* W_ih = (const float*)d_in[1];
    const float* W_hh = (const float*)d_in[2];
    const float* b_ih = (const float*)d_in[3];
    const float* b_hh = (const float*)d_in[4];
    const float* Wt   = (const float*)d_in[5];
    const float* bt   = (const float*)d_in[6];
    const float* Wf1  = (const float*)d_in[7];
    const float* bf1  = (const float*)d_in[8];
    const float* Wf2  = (const float*)d_in[9];
    const float* bf2  = (const float*)d_in[10];

    const int T = in_sizes[0] / (4 * D_IN);   // 16384

    float* carry = (float*)d_ws;                       // 256 floats
    float* xpbuf = (float*)((char*)d_ws + 1024);
    size_t avail = (ws_size > 1024) ? ws_size - 1024 : 0;

    // xp bytes per step: 4 LSTMs * 64 lanes * 16 B = 4096 B
    long cmax = (long)(avail / 4096);
    cmax = (cmax / 8) * 8;
    if (cmax > T) cmax = T;
    if (cmax < 8) cmax = 8;                            // assume ws >= ~40 KB

    int nch = (T + (int)cmax - 1) / (int)cmax;
    int cT0 = (T + nch - 1) / nch;
    cT0 = ((cT0 + 7) / 8) * 8;
    if (cT0 > (int)cmax) cT0 = (int)cmax;

    int done = 0;
    while (done < T) {
        int cT = (T - done < cT0) ? (T - done) : cT0;
        dim3 gx((cT + XT - 1) / XT, 4);
        xproj_kernel<<<gx, 128, 0, stream>>>(x, W_ih, b_ih, b_hh, xpbuf,
                                             done, cT, T);
        lstm_scan_m<<<4, 64, 0, stream>>>(xpbuf, W_hh, carry,
                                          cT, done == 0 ? 1 : 0);
        done += cT;
    }
    heads_kernel<<<1, 64, 0, stream>>>(carry, Wt, bt, Wf1, bf1, Wf2, bf2,
                                       (float*)d_out);
}